// Round 13
// baseline (207.559 us; speedup 1.0000x reference)
//
#include <hip/hip_runtime.h>
#include <math.h>

#define BB 4
#define LL 512000
#define NF 512
#define TT 3997
#define FF 257
#define TWO_PI 6.28318530717958647692f
// fl32(2*pi) — what the f32 numpy port uses building theta and window args:
#define TPI_F32 6.28318548202514648f

static const size_t SPEC_N = (size_t)BB * FF * TT;   // 4,108,916
static const size_t BNT    = (size_t)BB * NF * TT;   // 8,185,856
// layout A: spec | stft interleaved complex (2*BNT) | real | imag | phase = 40,961,256
// layout B (CONFIRMED r11): spec | stft real-part (BNT) | real | imag | phase = 32,775,400

#define AB_IM  3.0e-5f
#define RE_MAX 1.0e-4f
#define Z2_MIN 1.0e-8f

__device__ __forceinline__ float neg_zero() { return __uint_as_float(0x80000000u); }

// Barriered ops: exactly one IEEE-RN rounding each; asm barrier stops
// -ffp-contract=fast from fusing into fma where numpy has separate ops.
__device__ __forceinline__ float mulrn(float a, float b) { float t = a * b; asm("" : "+v"(t)); return t; }
__device__ __forceinline__ float addrn(float a, float b) { float t = a + b; asm("" : "+v"(t)); return t; }
// Single-rounded fused a*b+c (npyv_muladd on AVX512 = FMA):
__device__ __forceinline__ float fmarn(float a, float b, float c) { float t = fmaf(a, b, c); asm("" : "+v"(t)); return t; }

// np f32 theta: fl32(fl32(2pi)*k)/512  (k = f*n < 2^24 exact; /512 exact)
__device__ __forceinline__ float theta32(int k) {
    return mulrn(TPI_F32, (float)k) / 512.0f;
}

// _mm512_reduce_add_ps tree over 16 partials held by lanes base..base+15:
// u_k = s_k + s_{k+8}; v_k = u_k + u_{k+4}; r = (v0+v2) + (v1+v3)
__device__ __forceinline__ float hsum16(float s, int base) {
    float q[4];
#pragma unroll
    for (int k = 0; k < 4; ++k) {
        float a = addrn(__shfl(s, base + k),     __shfl(s, base + k + 8));
        float b = addrn(__shfl(s, base + k + 4), __shfl(s, base + k + 12));
        q[k] = addrn(a, b);
    }
    return addrn(addrn(q[0], q[2]), addrn(q[1], q[3]));
}

// ---------------------------------------------------------------------------
// Shared body. Emulates the f32 numpy gold at sign-critical bins:
//  window f32 ops (cos correctly rounded), psum sequential over n,
//  einsum = npyv AVX512 contig_two: lane L sums n≡L (mod 16); per 64-elem
//  iteration the four 16-elem blocks chain FORWARD
//  (acc+a0b0 -> +a1b1 -> +a2b2 -> +a3b3, FMA); AVX512 reduce tree.
__device__ __forceinline__ void dstft_frame_compute(
    const float* __restrict__ x,
    float strd, float wl, float wpow,
    float2* bufrow, float* exrow, const float* s256f, float2* tw,
    int lane, int t, int b, bool active, float* nyq_out)
{
    // frames[t] = t*clip(stride): f32 cumsum of 128.0 exact = f64 product
    double strd64  = fmin(fmax((double)strd, 0.0), 512.0);
    double frame64 = strd64 * (double)t;
    double frac64  = frame64 - floor(frame64);
    int    i0      = (int)floor(frame64);
    float  frac    = (float)frac64;

    // gold window (f32 ops; /2,/512 exact; cos correctly rounded)
    float shift = mulrn(addrn(wl - 512.0f, 1.0f), 0.5f);
    float lower = floorf(mulrn(511.0f - wl, 0.5f));
    float upper = ceilf (mulrn(511.0f + wl, 0.5f));

    float wv_[8];
#pragma unroll
    for (int j = 0; j < 8; ++j) {
        int n = lane + 64 * j;
        float base = (float)n - frac;
        float w = 0.0f;
        if (base > lower && base < upper) {
            float arg = mulrn(TPI_F32, addrn(base, shift)) / wl;
            w = 0.5f - mulrn(0.5f, (float)cos((double)arg));
        }
        wv_[j] = w;
        exrow[n] = w;
    }
    __syncthreads();

    // psum: np.sum(tap, axis=0) on (N,T) C-order = strictly sequential over n
    float ps = 0.0f;
    if (lane == 0) {
#pragma unroll 1
        for (int n = 0; n < NF; ++n) ps = addrn(ps, exrow[n]);
    }
    ps = __shfl(ps, 0);

    const bool dopow = (wpow != 1.0f);
#pragma unroll
    for (int j = 0; j < 8; ++j) {
        int n   = lane + 64 * j;
        int idx = i0 + n;
        float xv = (active && idx >= 0 && idx < LL) ? x[(size_t)b * LL + idx] : 0.0f;
        float ww = wv_[j] / ps;                 // np: tap / sum (f32 division)
        if (dopow) ww = powf(ww, wpow);
        float tap = mulrn(xv, ww);              // np: strided * tap
        exrow[n] = tap;                          // gold tapered, for emulation
        int rn = (int)(__brev((unsigned)n) >> 23);
        bufrow[rn] = make_float2(tap, 0.0f);
    }
    __syncthreads();

    for (int s = 0; s < 9; ++s) {                // radix-2 DIT FFT (fast path)
        int half = 1 << s;
#pragma unroll
        for (int it = 0; it < 4; ++it) {
            int j    = lane + 64 * it;
            int pos  = j & (half - 1);
            int idx0 = ((j >> s) << (s + 1)) + pos;
            float2 cA = bufrow[idx0];
            float2 cB = bufrow[idx0 + half];
            float2 w  = tw[pos << (8 - s)];
            float tr = w.x * cB.x - w.y * cB.y;
            float ti = w.x * cB.y + w.y * cB.x;
            bufrow[idx0]        = make_float2(cA.x + tr, cA.y + ti);
            bufrow[idx0 + half] = make_float2(cA.x - tr, cA.y - ti);
        }
        __syncthreads();
    }

    // imag[256] = -(npyv dot of tapered with sinf(theta32(256n))), FORWARD order
    {
        float s = 0.0f;
        if (lane < 16) {
#pragma unroll 1
            for (int i = 0; i < 8; ++i) {
                int base = 64 * i + lane;
                s = fmarn(exrow[base +  0], s256f[base +  0], s);
                s = fmarn(exrow[base + 16], s256f[base + 16], s);
                s = fmarn(exrow[base + 32], s256f[base + 32], s);
                s = fmarn(exrow[base + 48], s256f[base + 48], s);
            }
        }
        *nyq_out = -hsum16(s, 0);
    }

    // Flag scan: f=0/256 quadrant risk (|re| tiny); f 1..255 branch-cut risk.
    unsigned long long flags[4];
    unsigned long long anyf = 0ULL;
#pragma unroll
    for (int j = 0; j < 4; ++j) {
        int f = lane + 64 * j;
        float2 v = bufrow[f];
        bool flg;
        if (f == 0) flg = active && fabsf(v.x) < RE_MAX;
        else        flg = active &&
                          ((fabsf(v.y) < AB_IM && v.x < RE_MAX) ||
                           (v.x * v.x + v.y * v.y < Z2_MIN));
        flags[j] = __ballot(flg);
        anyf |= flags[j];
    }
    float2 v256 = bufrow[256];
    bool flag256 = active && fabsf(v256.x) < RE_MAX;

    if (anyf || flag256) {
        for (int jj = 0; jj < 5; ++jj) {
            unsigned long long m = (jj < 4) ? flags[jj] : (flag256 ? 1ULL : 0ULL);
            while (m) {
                int src = (int)(__ffsll(m) - 1);
                m &= m - 1;
                int ff = (jj < 4) ? (64 * jj + src) : 256;
                // lanes 0-15: sin partials; lanes 16-31: cos partials; FORWARD
                float s = 0.0f;
                if (lane < 32) {
                    int L = lane & 15;
                    bool isCos = lane >= 16;
#pragma unroll 1
                    for (int i = 0; i < 8; ++i) {
                        int base = 64 * i + L;
#pragma unroll
                        for (int B = 0; B < 4; ++B) {
                            int n = base + 16 * B;
                            double sv, cv;
                            sincos((double)theta32(ff * n), &sv, &cv);
                            s = fmarn(exrow[n], isCos ? (float)cv : (float)sv, s);
                        }
                    }
                }
                float im = hsum16(s, 0);
                float re = hsum16(s, 16);
                if (lane == src) bufrow[ff] = make_float2(re, -im);
            }
        }
    }
    __syncthreads();
}

// ---------------------------------------------------------------------------
__global__ __launch_bounds__(256) void dstft_fft_kernel(
    const float* __restrict__ x,
    const float* __restrict__ p_stride,
    const float* __restrict__ p_winlen,
    const float* __restrict__ p_winpow,
    float2* __restrict__ scr, size_t scr_cap)
{
    __shared__ float2 tw[256];
    __shared__ float2 buf[4][NF];
    __shared__ float  ex[4][NF];
    __shared__ float  s256f[NF];

    const int tid  = threadIdx.x;
    const int wv   = tid >> 6;
    const int lane = tid & 63;

    {
        float s, c;
        sincosf(-(TWO_PI / 512.0f) * (float)tid, &s, &c);
        tw[tid] = make_float2(c, s);
        for (int k = tid; k < NF; k += 256)
            s256f[k] = (float)sin((double)theta32(256 * k));
    }
    __syncthreads();

    float strd = p_stride[0];
    float wl   = fminf(fmaxf(p_winlen[0], (float)(512.0 / 20.0)), 512.0f);
    float wpow = p_winpow[0];

    const int t = blockIdx.x * 4 + wv;
    const int b = blockIdx.y;
    const bool active = (t < TT);

    float nyq;
    dstft_frame_compute(x, strd, wl, wpow, buf[wv], ex[wv], s256f, tw,
                        lane, t, b, active, &nyq);

    if (active) {
        size_t basez = ((size_t)b * TT + t) * NF;
#pragma unroll
        for (int j = 0; j < 8; ++j) {
            int f = lane + 64 * j;
            float2 v = buf[wv][f];
            if (f == 0)   v.y = neg_zero();  // gold FMA chain: -(+0.0) = -0.0
            if (f == 256) v.y = nyq;         // gold forward-npyv Nyquist value
            if (basez + f < scr_cap) scr[basez + f] = v;
        }
    }
}

// ---------------------------------------------------------------------------
__global__ __launch_bounds__(256) void dstft_epilogue(
    const float2* __restrict__ scr, size_t scr_cap,
    float* __restrict__ out, size_t oe, int layoutB)
{
    __shared__ float2 tile[32][33];
    const int tx = threadIdx.x;          // 0..31
    const int ty = threadIdx.y;          // 0..7
    const int t0 = blockIdx.x * 32;
    const int f0 = blockIdx.y * 32;
    const int b  = blockIdx.z;

#pragma unroll
    for (int i = 0; i < 4; ++i) {
        int tl = ty + 8 * i;
        int t  = t0 + tl;
        float2 v = make_float2(0.0f, 0.0f);
        size_t si = ((size_t)b * TT + t) * NF + (f0 + tx);
        if (t < TT && si < scr_cap) v = scr[si];
        tile[tl][tx] = v;
    }
    __syncthreads();

    const size_t off_stft  = SPEC_N;
    const size_t off_real  = layoutB ? (SPEC_N + BNT) : (SPEC_N + 2 * BNT);
    const size_t off_imag  = off_real + BNT;
    const size_t off_phase = off_imag + BNT;

#pragma unroll
    for (int i = 0; i < 4; ++i) {
        int fl = ty + 8 * i;
        int f  = f0 + fl;
        int t  = t0 + tx;
        if (t >= TT) continue;
        float2 v = tile[tx][fl];
        size_t o = ((size_t)b * NF + f) * TT + t;
        if (off_real + o < oe) out[off_real + o] = v.x;
        if (off_imag + o < oe) out[off_imag + o] = v.y;
        if (layoutB) {
            if (off_stft + o < oe) out[off_stft + o] = v.x;
        } else {
            size_t os = off_stft + 2 * o;
            if (os + 1 < oe) *reinterpret_cast<float2*>(out + os) = v;
        }
        if (f < FF) {
            size_t o2 = ((size_t)b * FF + f) * TT + t;
            if (o2 < oe) out[o2] = sqrtf(v.x * v.x + v.y * v.y) + 1.1920929e-7f;
            if (off_phase + o2 < oe) out[off_phase + o2] = atan2f(v.y, v.x);
        }
    }
}

// ---------------------------------------------------------------------------
// Fallback (ws too small): fused compute + direct writes.
__global__ __launch_bounds__(256) void dstft_fused(
    const float* __restrict__ x,
    const float* __restrict__ p_stride,
    const float* __restrict__ p_winlen,
    const float* __restrict__ p_winpow,
    float* __restrict__ out, size_t oe, int layoutB)
{
    __shared__ float2 tw[256];
    __shared__ float2 buf[4][NF];
    __shared__ float  ex[4][NF];
    __shared__ float  s256f[NF];

    const int tid  = threadIdx.x;
    const int wv   = tid >> 6;
    const int lane = tid & 63;

    {
        float s, c;
        sincosf(-(TWO_PI / 512.0f) * (float)tid, &s, &c);
        tw[tid] = make_float2(c, s);
        for (int k = tid; k < NF; k += 256)
            s256f[k] = (float)sin((double)theta32(256 * k));
    }
    __syncthreads();

    float strd = p_stride[0];
    float wl   = fminf(fmaxf(p_winlen[0], (float)(512.0 / 20.0)), 512.0f);
    float wpow = p_winpow[0];

    const int t = blockIdx.x * 4 + wv;
    const int b = blockIdx.y;
    const bool active = (t < TT);

    float nyq;
    dstft_frame_compute(x, strd, wl, wpow, buf[wv], ex[wv], s256f, tw,
                        lane, t, b, active, &nyq);

    if (active) {
        const size_t off_stft  = SPEC_N;
        const size_t off_real  = layoutB ? (SPEC_N + BNT) : (SPEC_N + 2 * BNT);
        const size_t off_imag  = off_real + BNT;
        const size_t off_phase = off_imag + BNT;
#pragma unroll
        for (int j = 0; j < 8; ++j) {
            int f = lane + 64 * j;
            float2 v = buf[wv][f];
            if (f == 0)   v.y = neg_zero();
            if (f == 256) v.y = nyq;
            size_t o = ((size_t)b * NF + f) * TT + t;
            if (off_real + o < oe) out[off_real + o] = v.x;
            if (off_imag + o < oe) out[off_imag + o] = v.y;
            if (layoutB) {
                if (off_stft + o < oe) out[off_stft + o] = v.x;
            } else {
                size_t os = off_stft + 2 * o;
                if (os + 1 < oe) { out[os] = v.x; out[os + 1] = v.y; }
            }
            if (f < FF) {
                size_t o2 = ((size_t)b * FF + f) * TT + t;
                if (o2 < oe) out[o2] = sqrtf(v.x * v.x + v.y * v.y) + 1.1920929e-7f;
                if (off_phase + o2 < oe) out[off_phase + o2] = atan2f(v.y, v.x);
            }
        }
    }
}

// ---------------------------------------------------------------------------
extern "C" void kernel_launch(void* const* d_in, const int* in_sizes, int n_in,
                              void* d_out, int out_size, void* d_ws, size_t ws_size,
                              hipStream_t stream)
{
    const float* x  = (const float*)d_in[0];
    const float* ps = (const float*)d_in[1];
    const float* pw = (const float*)d_in[2];
    const float* pp = (const float*)d_in[3];
    float* out = (float*)d_out;

    const size_t totalA = 2 * SPEC_N + 4 * BNT;   // 40,961,256
    int layoutB = ((size_t)out_size == totalA) ? 0 : 1;   // confirmed: B

    const size_t oe = (size_t)out_size;
    const size_t scrBytes = BNT * sizeof(float2);   // 65.5 MB
    const bool use_ws = (d_ws != nullptr) && (ws_size >= scrBytes);

    if (use_ws) {
        float2* scr = (float2*)d_ws;
        dstft_fft_kernel<<<dim3((TT + 3) / 4, BB), 256, 0, stream>>>(
            x, ps, pw, pp, scr, BNT);
        dstft_epilogue<<<dim3((TT + 31) / 32, NF / 32, BB), dim3(32, 8), 0, stream>>>(
            scr, BNT, out, oe, layoutB);
    } else {
        dstft_fused<<<dim3((TT + 3) / 4, BB), 256, 0, stream>>>(
            x, ps, pw, pp, out, oe, layoutB);
    }
}

// Round 14
// 159.125 us; speedup vs baseline: 1.3044x; 1.3044x over previous
//
#include <hip/hip_runtime.h>
#include <math.h>

#define BB 4
#define LL 512000
#define NF 512
#define TT 3997
#define FF 257
#define TWO_PI 6.28318530717958647692f
// fl32(2*pi) — what the f32 numpy port uses building theta and window args:
#define TPI_F32 6.28318548202514648f

static const size_t SPEC_N = (size_t)BB * FF * TT;   // 4,108,916
static const size_t BNT    = (size_t)BB * NF * TT;   // 8,185,856
// layout B (confirmed r11): spec | stft real-part (BNT) | real | imag | phase

#define AB_IM  3.0e-5f
#define RE_MAX 1.0e-4f
#define Z2_MIN 1.0e-8f

__device__ __forceinline__ float neg_zero() { return __uint_as_float(0x80000000u); }

// Barriered ops: exactly one IEEE-RN rounding each; asm barrier stops
// -ffp-contract=fast from fusing into fma where numpy has separate ops.
__device__ __forceinline__ float mulrn(float a, float b) { float t = a * b; asm("" : "+v"(t)); return t; }
__device__ __forceinline__ float addrn(float a, float b) { float t = a + b; asm("" : "+v"(t)); return t; }
// Single-rounded fused a*b+c (npyv_muladd on AVX512 = FMA):
__device__ __forceinline__ float fmarn(float a, float b, float c) { float t = fmaf(a, b, c); asm("" : "+v"(t)); return t; }

// np f32 theta: fl32(fl32(2pi)*k)/512  (k = f*n < 2^24 exact; /512 exact)
__device__ __forceinline__ float theta32(int k) {
    return mulrn(TPI_F32, (float)k) / 512.0f;
}

// Wave-private LDS sync: buffers are per-wave, no cross-wave rendezvous needed.
// (rule #18: sched_barrier after inline-asm waitcnt)
#define WAVE_SYNC() do { asm volatile("s_waitcnt lgkmcnt(0)" ::: "memory"); \
                         __builtin_amdgcn_sched_barrier(0); } while (0)

// _mm512_reduce_add_ps tree over 16 partials held by lanes base..base+15
__device__ __forceinline__ float hsum16(float s, int base) {
    float q[4];
#pragma unroll
    for (int k = 0; k < 4; ++k) {
        float a = addrn(__shfl(s, base + k),     __shfl(s, base + k + 8));
        float b = addrn(__shfl(s, base + k + 4), __shfl(s, base + k + 12));
        q[k] = addrn(a, b);
    }
    return addrn(addrn(q[0], q[2]), addrn(q[1], q[3]));
}

// ---------------------------------------------------------------------------
// Setup: s256f[n] = fl32(sin_f64(theta32(256n))) — f32-theta sin basis row.
__global__ void dstft_sin256(float* __restrict__ s256g)
{
    int n = threadIdx.x;   // 512 threads
    s256g[n] = (float)sin((double)theta32(256 * n));
}

// ---------------------------------------------------------------------------
// Shared body: fast cosf window + parallel psum + FFT; gold (f64-window,
// seq-psum, npyv-order) recompute only for flagged frames.
__device__ __forceinline__ void dstft_frame_compute(
    const float* __restrict__ x,
    float strd, float wl, float wpow,
    float2* bufrow, float* exrow, const float* s256f, float2* tw,
    int lane, int t, int b, bool active, float* nyq_out)
{
    double strd64  = fmin(fmax((double)strd, 0.0), 512.0);
    double frame64 = strd64 * (double)t;
    double frac64  = frame64 - floor(frame64);
    int    i0      = (int)floor(frame64);
    float  frac    = (float)frac64;

    // ---- fast path window (cosf) + wave-parallel psum
    float shift = (wl - 511.0f) * 0.5f;
    float lower = floorf((511.0f - wl) * 0.5f);
    float upper = ceilf ((511.0f + wl) * 0.5f);

    float wv_[8];
    float psum = 0.0f;
#pragma unroll
    for (int j = 0; j < 8; ++j) {
        int n = lane + 64 * j;
        float base = (float)n - frac;
        float w = 0.0f;
        if (base > lower && base < upper)
            w = 0.5f - 0.5f * cosf(TWO_PI * (base + shift) / wl);
        wv_[j] = w;
        psum += w;
    }
#pragma unroll
    for (int off = 32; off > 0; off >>= 1) psum += __shfl_xor(psum, off);
    float inv = 1.0f / psum;

    const bool dopow = (wpow != 1.0f);
    float xraw[8];
#pragma unroll
    for (int j = 0; j < 8; ++j) {
        int n   = lane + 64 * j;
        int idx = i0 + n;
        float xv = (active && idx >= 0 && idx < LL) ? x[(size_t)b * LL + idx] : 0.0f;
        xraw[j] = xv;
        float ww = wv_[j] * inv;
        if (dopow) ww = powf(ww, wpow);
        float tap = xv * ww;
        exrow[n] = tap;
        int rn = (int)(__brev((unsigned)n) >> 23);
        bufrow[rn] = make_float2(tap, 0.0f);
    }
    WAVE_SYNC();

    for (int s = 0; s < 9; ++s) {                // radix-2 DIT FFT
        int half = 1 << s;
#pragma unroll
        for (int it = 0; it < 4; ++it) {
            int j    = lane + 64 * it;
            int pos  = j & (half - 1);
            int idx0 = ((j >> s) << (s + 1)) + pos;
            float2 cA = bufrow[idx0];
            float2 cB = bufrow[idx0 + half];
            float2 w  = tw[pos << (8 - s)];
            float tr = w.x * cB.x - w.y * cB.y;
            float ti = w.x * cB.y + w.y * cB.x;
            bufrow[idx0]        = make_float2(cA.x + tr, cA.y + ti);
            bufrow[idx0 + half] = make_float2(cA.x - tr, cA.y - ti);
        }
        WAVE_SYNC();
    }

    // imag[256] = -(npyv forward dot of taps with s256f) — always
    {
        float s = 0.0f;
        if (lane < 16) {
#pragma unroll 1
            for (int i = 0; i < 8; ++i) {
                int base = 64 * i + lane;
                s = fmarn(exrow[base +  0], s256f[base +  0], s);
                s = fmarn(exrow[base + 16], s256f[base + 16], s);
                s = fmarn(exrow[base + 32], s256f[base + 32], s);
                s = fmarn(exrow[base + 48], s256f[base + 48], s);
            }
        }
        *nyq_out = -hsum16(s, 0);
    }

    // Flag scan: f=0/256 quadrant risk (|re| tiny); f 1..255 branch-cut risk.
    unsigned long long flags[4];
    unsigned long long anyf = 0ULL;
#pragma unroll
    for (int j = 0; j < 4; ++j) {
        int f = lane + 64 * j;
        float2 v = bufrow[f];
        bool flg;
        if (f == 0) flg = active && fabsf(v.x) < RE_MAX;
        else        flg = active &&
                          ((fabsf(v.y) < AB_IM && v.x < RE_MAX) ||
                           (v.x * v.x + v.y * v.y < Z2_MIN));
        flags[j] = __ballot(flg);
        anyf |= flags[j];
    }
    float2 v256 = bufrow[256];
    bool flag256 = active && fabsf(v256.x) < RE_MAX;

    if (anyf || flag256) {
        // ---- gold window (f32 ops, f64-rounded cos) — R13-verified sequence
        float g_shift = mulrn(addrn(wl - 512.0f, 1.0f), 0.5f);
        float g_lower = floorf(mulrn(511.0f - wl, 0.5f));
        float g_upper = ceilf (mulrn(511.0f + wl, 0.5f));
        float gw[8];
#pragma unroll
        for (int j = 0; j < 8; ++j) {
            int n = lane + 64 * j;
            float base = (float)n - frac;
            float w = 0.0f;
            if (base > g_lower && base < g_upper) {
                float arg = mulrn(TPI_F32, addrn(base, g_shift)) / wl;
                w = 0.5f - mulrn(0.5f, (float)cos((double)arg));
            }
            gw[j] = w;
            exrow[n] = w;
        }
        WAVE_SYNC();
        // psum: np.sum(axis=0) = strictly sequential over n
        float ps = 0.0f;
        if (lane == 0) {
#pragma unroll 1
            for (int n = 0; n < NF; ++n) ps = addrn(ps, exrow[n]);
        }
        ps = __shfl(ps, 0);
#pragma unroll
        for (int j = 0; j < 8; ++j) {
            int n = lane + 64 * j;
            float ww = gw[j] / ps;                 // np: tap / sum (f32 div)
            if (dopow) ww = powf(ww, wpow);
            exrow[n] = mulrn(xraw[j], ww);         // gold tapered
        }
        WAVE_SYNC();

        for (int jj = 0; jj < 5; ++jj) {
            unsigned long long m = (jj < 4) ? flags[jj] : (flag256 ? 1ULL : 0ULL);
            while (m) {
                int src = (int)(__ffsll(m) - 1);
                m &= m - 1;
                int ff = (jj < 4) ? (64 * jj + src) : 256;
                // lanes 0-15: sin partials; 16-31: cos partials; FORWARD chain
                float s = 0.0f;
                if (lane < 32) {
                    int L = lane & 15;
                    bool isCos = lane >= 16;
#pragma unroll 1
                    for (int i = 0; i < 8; ++i) {
                        int base = 64 * i + L;
#pragma unroll
                        for (int B = 0; B < 4; ++B) {
                            int n = base + 16 * B;
                            double sv, cv;
                            sincos((double)theta32(ff * n), &sv, &cv);
                            s = fmarn(exrow[n], isCos ? (float)cv : (float)sv, s);
                        }
                    }
                }
                float im = hsum16(s, 0);
                float re = hsum16(s, 16);
                if (lane == src) bufrow[ff] = make_float2(re, -im);
            }
        }
        // gold imag[256] when flagged frame touched bin 256 handled above;
        // recompute nyq from gold taps for consistency of the always-set value
        {
            float s = 0.0f;
            if (lane < 16) {
#pragma unroll 1
                for (int i = 0; i < 8; ++i) {
                    int base = 64 * i + lane;
                    s = fmarn(exrow[base +  0], s256f[base +  0], s);
                    s = fmarn(exrow[base + 16], s256f[base + 16], s);
                    s = fmarn(exrow[base + 32], s256f[base + 32], s);
                    s = fmarn(exrow[base + 48], s256f[base + 48], s);
                }
            }
            *nyq_out = -hsum16(s, 0);
        }
    }
    WAVE_SYNC();
}

// ---------------------------------------------------------------------------
__global__ __launch_bounds__(256) void dstft_fft_kernel(
    const float* __restrict__ x,
    const float* __restrict__ p_stride,
    const float* __restrict__ p_winlen,
    const float* __restrict__ p_winpow,
    const float* __restrict__ s256g,
    float2* __restrict__ scr, size_t scr_cap)
{
    __shared__ float2 tw[256];
    __shared__ float2 buf[4][NF];
    __shared__ float  ex[4][NF];
    __shared__ float  s256f[NF];

    const int tid  = threadIdx.x;
    const int wv   = tid >> 6;
    const int lane = tid & 63;

    {
        float s, c;
        sincosf(-(TWO_PI / 512.0f) * (float)tid, &s, &c);
        tw[tid] = make_float2(c, s);
        s256f[tid]       = s256g[tid];
        s256f[tid + 256] = s256g[tid + 256];
    }
    __syncthreads();   // cross-wave: tw + s256f shared by all waves

    float strd = p_stride[0];
    float wl   = fminf(fmaxf(p_winlen[0], (float)(512.0 / 20.0)), 512.0f);
    float wpow = p_winpow[0];

    const int t = blockIdx.x * 4 + wv;
    const int b = blockIdx.y;
    const bool active = (t < TT);

    float nyq;
    dstft_frame_compute(x, strd, wl, wpow, buf[wv], ex[wv], s256f, tw,
                        lane, t, b, active, &nyq);

    if (active) {
        size_t basez = ((size_t)b * TT + t) * NF;
#pragma unroll
        for (int j = 0; j < 8; ++j) {
            int f = lane + 64 * j;
            float2 v = buf[wv][f];
            if (f == 0)   v.y = neg_zero();  // gold FMA chain: -(+0.0) = -0.0
            if (f == 256) v.y = nyq;         // gold forward-npyv Nyquist value
            if (basez + f < scr_cap) scr[basez + f] = v;
        }
    }
}

// ---------------------------------------------------------------------------
__global__ __launch_bounds__(256) void dstft_epilogue(
    const float2* __restrict__ scr, size_t scr_cap,
    float* __restrict__ out, size_t oe, int layoutB)
{
    __shared__ float2 tile[32][33];
    const int tx = threadIdx.x;          // 0..31
    const int ty = threadIdx.y;          // 0..7
    const int t0 = blockIdx.x * 32;
    const int f0 = blockIdx.y * 32;
    const int b  = blockIdx.z;

#pragma unroll
    for (int i = 0; i < 4; ++i) {
        int tl = ty + 8 * i;
        int t  = t0 + tl;
        float2 v = make_float2(0.0f, 0.0f);
        size_t si = ((size_t)b * TT + t) * NF + (f0 + tx);
        if (t < TT && si < scr_cap) v = scr[si];
        tile[tl][tx] = v;
    }
    __syncthreads();

    const size_t off_stft  = SPEC_N;
    const size_t off_real  = layoutB ? (SPEC_N + BNT) : (SPEC_N + 2 * BNT);
    const size_t off_imag  = off_real + BNT;
    const size_t off_phase = off_imag + BNT;

#pragma unroll
    for (int i = 0; i < 4; ++i) {
        int fl = ty + 8 * i;
        int f  = f0 + fl;
        int t  = t0 + tx;
        if (t >= TT) continue;
        float2 v = tile[tx][fl];
        size_t o = ((size_t)b * NF + f) * TT + t;
        if (off_real + o < oe) out[off_real + o] = v.x;
        if (off_imag + o < oe) out[off_imag + o] = v.y;
        if (layoutB) {
            if (off_stft + o < oe) out[off_stft + o] = v.x;
        } else {
            size_t os = off_stft + 2 * o;
            if (os + 1 < oe) *reinterpret_cast<float2*>(out + os) = v;
        }
        if (f < FF) {
            size_t o2 = ((size_t)b * FF + f) * TT + t;
            if (o2 < oe) out[o2] = sqrtf(v.x * v.x + v.y * v.y) + 1.1920929e-7f;
            if (off_phase + o2 < oe) out[off_phase + o2] = atan2f(v.y, v.x);
        }
    }
}

// ---------------------------------------------------------------------------
// Fallback (ws too small): fused compute + direct writes.
__global__ __launch_bounds__(256) void dstft_fused(
    const float* __restrict__ x,
    const float* __restrict__ p_stride,
    const float* __restrict__ p_winlen,
    const float* __restrict__ p_winpow,
    float* __restrict__ out, size_t oe, int layoutB)
{
    __shared__ float2 tw[256];
    __shared__ float2 buf[4][NF];
    __shared__ float  ex[4][NF];
    __shared__ float  s256f[NF];

    const int tid  = threadIdx.x;
    const int wv   = tid >> 6;
    const int lane = tid & 63;

    {
        float s, c;
        sincosf(-(TWO_PI / 512.0f) * (float)tid, &s, &c);
        tw[tid] = make_float2(c, s);
        for (int k = tid; k < NF; k += 256)
            s256f[k] = (float)sin((double)theta32(256 * k));
    }
    __syncthreads();

    float strd = p_stride[0];
    float wl   = fminf(fmaxf(p_winlen[0], (float)(512.0 / 20.0)), 512.0f);
    float wpow = p_winpow[0];

    const int t = blockIdx.x * 4 + wv;
    const int b = blockIdx.y;
    const bool active = (t < TT);

    float nyq;
    dstft_frame_compute(x, strd, wl, wpow, buf[wv], ex[wv], s256f, tw,
                        lane, t, b, active, &nyq);

    if (active) {
        const size_t off_stft  = SPEC_N;
        const size_t off_real  = layoutB ? (SPEC_N + BNT) : (SPEC_N + 2 * BNT);
        const size_t off_imag  = off_real + BNT;
        const size_t off_phase = off_imag + BNT;
#pragma unroll
        for (int j = 0; j < 8; ++j) {
            int f = lane + 64 * j;
            float2 v = buf[wv][f];
            if (f == 0)   v.y = neg_zero();
            if (f == 256) v.y = nyq;
            size_t o = ((size_t)b * NF + f) * TT + t;
            if (off_real + o < oe) out[off_real + o] = v.x;
            if (off_imag + o < oe) out[off_imag + o] = v.y;
            if (layoutB) {
                if (off_stft + o < oe) out[off_stft + o] = v.x;
            } else {
                size_t os = off_stft + 2 * o;
                if (os + 1 < oe) { out[os] = v.x; out[os + 1] = v.y; }
            }
            if (f < FF) {
                size_t o2 = ((size_t)b * FF + f) * TT + t;
                if (o2 < oe) out[o2] = sqrtf(v.x * v.x + v.y * v.y) + 1.1920929e-7f;
                if (off_phase + o2 < oe) out[off_phase + o2] = atan2f(v.y, v.x);
            }
        }
    }
}

// ---------------------------------------------------------------------------
extern "C" void kernel_launch(void* const* d_in, const int* in_sizes, int n_in,
                              void* d_out, int out_size, void* d_ws, size_t ws_size,
                              hipStream_t stream)
{
    const float* x  = (const float*)d_in[0];
    const float* ps = (const float*)d_in[1];
    const float* pw = (const float*)d_in[2];
    const float* pp = (const float*)d_in[3];
    float* out = (float*)d_out;

    const size_t totalA = 2 * SPEC_N + 4 * BNT;   // 40,961,256
    int layoutB = ((size_t)out_size == totalA) ? 0 : 1;   // confirmed: B

    const size_t oe = (size_t)out_size;
    const size_t scrBytes = BNT * sizeof(float2);          // 65.5 MB
    const size_t needWs   = scrBytes + NF * sizeof(float); // + sin table
    const bool use_ws = (d_ws != nullptr) && (ws_size >= needWs);

    if (use_ws) {
        float2* scr   = (float2*)d_ws;
        float*  s256g = (float*)((char*)d_ws + scrBytes);
        dstft_sin256<<<1, NF, 0, stream>>>(s256g);
        dstft_fft_kernel<<<dim3((TT + 3) / 4, BB), 256, 0, stream>>>(
            x, ps, pw, pp, s256g, scr, BNT);
        dstft_epilogue<<<dim3((TT + 31) / 32, NF / 32, BB), dim3(32, 8), 0, stream>>>(
            scr, BNT, out, oe, layoutB);
    } else {
        dstft_fused<<<dim3((TT + 3) / 4, BB), 256, 0, stream>>>(
            x, ps, pw, pp, out, oe, layoutB);
    }
}